// Round 6
// baseline (5710.209 us; speedup 1.0000x reference)
//
#include <hip/hip_runtime.h>
#include <cstdint>

#define TT 128   // time steps (= bucket_size)
#define BB 128   // batch
#define II 512   // input dim
#define HH 512   // hidden dim
#define DD 1024  // I + H
#define NC 513   // H + 1
#define NPAD 520 // row pitch for lnXW / vbuf (bf16)
#define NT 36    // n-tiles of 16 in big GEMM (576 padded cols)
#define EPSL 1e-5f

typedef short    s8v  __attribute__((ext_vector_type(8)));
typedef float    f4v  __attribute__((ext_vector_type(4)));
typedef _Float16 h2v  __attribute__((ext_vector_type(2)));

__device__ __forceinline__ ushort f2bf(float f){
  uint u = __builtin_bit_cast(uint, f);
  uint r = (u + 0x7fffu + ((u >> 16) & 1u)) >> 16;
  return (ushort)r;
}
__device__ __forceinline__ float bf2f(ushort s){
  uint u = ((uint)s) << 16;
  return __builtin_bit_cast(float, u);
}
__device__ __forceinline__ float hsig(float x){
  return fminf(fmaxf(0.2f * x + 0.5f, 0.f), 1.f);
}
// fast tanh via exp2; |err| ~1e-6
__device__ __forceinline__ float ftanh(float x){
  float ax = fminf(fabsf(x), 15.f);
  float e  = __builtin_amdgcn_exp2f(ax * 2.885390082f);   // 2*log2(e)
  float r  = (e - 1.f) * __builtin_amdgcn_rcpf(e + 1.f);
  return __builtin_copysignf(r, x);
}
// f32 += dot(f16x2, f16x2) — exact products, f32 accumulate
__device__ __forceinline__ float dot2(uint a, uint b, float c){
#if __has_builtin(__builtin_amdgcn_fdot2)
  return __builtin_amdgcn_fdot2(__builtin_bit_cast(h2v, a),
                                __builtin_bit_cast(h2v, b), c, false);
#else
  h2v x = __builtin_bit_cast(h2v, a), y = __builtin_bit_cast(h2v, b);
  return fmaf((float)x[1], (float)y[1], fmaf((float)x[0], (float)y[0], c));
#endif
}

// ---------------- pre-pack W / U into MFMA B-fragment order (bf16, big GEMM) ----
__global__ void prepack_B(const float* __restrict__ src, ushort* __restrict__ dst){
  int idx = blockIdx.x * 256 + threadIdx.x;
  if (idx >= 128 * NT * 16 * 8) return;
  int kl = idx & 7;
  int ni = (idx >> 3) & 15;
  int nt = (idx >> 7) % NT;
  int kc = idx / (NT * 16 * 8);
  int k = kc * 8 + kl;
  int n = nt * 16 + ni;
  float v = (n < NC) ? src[k * NC + n] : 0.f;
  dst[idx] = f2bf(v);
}

// ---------------- pre-pack U_hi (rows II..II+511) as f16 pairs for fdot2 --------
// uint idx = (c*512 + n)*4 + j holds f16 pair (U[II+8c+2j][n], U[II+8c+2j+1][n]).
__global__ void prepack_Uhi_pk(const float* __restrict__ U, uint* __restrict__ dst,
                               float* __restrict__ ucol){
  int idx = blockIdx.x * 256 + threadIdx.x;
  if (idx < 64 * 512 * 4){
    int j = idx & 3;
    int n = (idx >> 2) & 511;
    int c = idx >> 11;
    int k0 = II + 8 * c + 2 * j;
    _Float16 lo = (_Float16)U[(size_t)k0 * NC + n];
    _Float16 hi = (_Float16)U[(size_t)(k0 + 1) * NC + n];
    dst[idx] = (uint)__builtin_bit_cast(ushort, lo)
             | ((uint)__builtin_bit_cast(ushort, hi) << 16);
  }
  if (idx < 512) ucol[idx] = U[(size_t)(II + idx) * NC + 512];
}

// ---------------- fused GEMM (+ optional row-LayerNorm) -------------------
__global__ __launch_bounds__(1024) void gemm_ln(
    const float* __restrict__ A, int amode, int ksteps,
    const ushort* __restrict__ Bpk, ushort* __restrict__ out,
    int do_ln, const float* __restrict__ gam, const float* __restrict__ bet,
    const float* __restrict__ bias)
{
  __shared__ ushort As[64][40];
  __shared__ float red[4][4][16][2];
  int tid = threadIdx.x;
  int lane = tid & 63, wid = tid >> 6;
  int quad = lane >> 4, l16 = lane & 15;
  int wm = wid >> 2, wn = wid & 3;
  int blk = blockIdx.x;

  f4v acc[9];
#pragma unroll
  for (int i = 0; i < 9; i++) acc[i] = (f4v){0.f, 0.f, 0.f, 0.f};

  int arow = tid >> 4;
  int acp  = tid & 15;
  int r = blk * 64 + arow;
  const float* aptr;
  if (amode == 0){ int t = r >> 7, b = r & 127; aptr = A + ((size_t)(b * TT + t)) * II + acp * 2; }
  else           { aptr = A + (size_t)r * DD + acp * 2; }

  for (int ks = 0; ks < ksteps; ks++){
    __syncthreads();
    float2 a2 = *(const float2*)(aptr + ks * 32);
    uint pk = (uint)f2bf(a2.x) | ((uint)f2bf(a2.y) << 16);
    *(uint*)&As[arow][acp * 2] = pk;
    __syncthreads();
    s8v af = *(const s8v*)&As[wm * 16 + l16][quad * 8];
    int kc = ks * 4 + quad;
    const s8v* bp = (const s8v*)Bpk + (size_t)kc * (NT * 16) + l16;
#pragma unroll
    for (int i = 0; i < 9; i++){
      s8v bf = bp[(wn * 9 + i) * 16];
      acc[i] = __builtin_amdgcn_mfma_f32_16x16x32_bf16(af, bf, acc[i], 0, 0, 0);
    }
  }

  int rowbase = blk * 64 + wm * 16 + quad * 4;
  if (do_ln){
    float s1[4], s2[4];
#pragma unroll
    for (int g = 0; g < 4; g++){
      float a = 0.f, q = 0.f;
#pragma unroll
      for (int i = 0; i < 9; i++){ float v = acc[i][g]; a += v; q += v * v; }
#pragma unroll
      for (int m = 1; m < 16; m <<= 1){ a += __shfl_xor(a, m, 64); q += __shfl_xor(q, m, 64); }
      s1[g] = a; s2[g] = q;
    }
    if (l16 == 0){
#pragma unroll
      for (int g = 0; g < 4; g++){
        red[wm][wn][quad * 4 + g][0] = s1[g];
        red[wm][wn][quad * 4 + g][1] = s2[g];
      }
    }
    __syncthreads();
#pragma unroll
    for (int g = 0; g < 4; g++){
      int rr = quad * 4 + g;
      float S1 = red[wm][0][rr][0] + red[wm][1][rr][0] + red[wm][2][rr][0] + red[wm][3][rr][0];
      float S2 = red[wm][0][rr][1] + red[wm][1][rr][1] + red[wm][2][rr][1] + red[wm][3][rr][1];
      float mean = S1 * (1.f / 513.f);
      float var  = S2 * (1.f / 513.f) - mean * mean;
      float inv  = 1.f / (sqrtf(var + EPSL) + EPSL);
      size_t rg = (size_t)(rowbase + g);
#pragma unroll
      for (int i = 0; i < 9; i++){
        int n = wn * 144 + i * 16 + l16;
        if (n < NC){
          float val = gam[n] * ((acc[i][g] - mean) * inv) + bet[n] + bias[n];
          out[rg * NPAD + n] = f2bf(val);
        }
      }
    }
  } else {
#pragma unroll
    for (int g = 0; g < 4; g++){
      size_t rg = (size_t)(rowbase + g);
#pragma unroll
      for (int i = 0; i < 9; i++){
        int n = wn * 144 + i * 16 + l16;
        if (n < NC) out[rg * NPAD + n] = f2bf(acc[i][g]);
      }
    }
  }
}

// ---------------- recurrence: TWO batch rows per block (intra-block only) ----
// grid = 64 blocks; block handles rows bA=2*blk, bB=2*blk+1; 512 threads = 8
// waves; thread n owns column n of both rows. One U load per GEMV iteration
// feeds both rows (8 dot2) -> U L2 traffic and the fixed per-step chain
// (barriers, reductions, gates, load latencies) are amortized over 2 rows.
// 2 barriers/step; col-512 + LN stats merged in one 6-value shuffle chain.
__global__ __launch_bounds__(512) void rnn_layer(
    int layer,
    const float* __restrict__ x,
    float* __restrict__ h_seq,
    const ushort* __restrict__ lnXW,
    ushort* __restrict__ vbuf,
    float* __restrict__ fkbuf,
    float* __restrict__ hvbuf,
    const uint* __restrict__ Upk4,
    const float* __restrict__ ucol,
    const int* __restrict__ mask,
    const float* __restrict__ gam1, const float* __restrict__ bet1,
    const float* __restrict__ bias,
    float* __restrict__ out)
{
  __shared__ __align__(16) ushort tanhA[512], tanhB[512];  // f16 tanh (GEMV)
  __shared__ __align__(16) float  tvfA[512],  tvfB[512];   // f32 tanh
  __shared__ float redS[8][6];   // per wave: aA qA pA aB qB pB
  __shared__ float sh_v0A, sh_v0B;
  __shared__ int mskA[TT], mskB[TT];

  int tid = threadIdx.x;
  int bA = 2 * blockIdx.x, bB = bA + 1;
  int lane = tid & 63, wid = tid >> 6;
  const bool lastL = (layer == 3);

  // per-row persistent state
  float svA = 0.f, svB = 0.f;
  float v5A = 0.f, v5B = 0.f;            // uniform col-512 state
  float hloA = 0.f, hloB = 0.f, hhiA = 0.f, hhiB = 0.f;
  float fkcA = 0.f, fkcB = 0.f, hvcA = 0.f, hvcB = 0.f;
  float hoA = 0.f, xoA = 0.f, boA = 0.f, xu5pA = 0.f; int mkpA = 0;
  float hoB = 0.f, xoB = 0.f, boB = 0.f, xu5pB = 0.f; int mkpB = 0;

  float g1n = gam1[tid], b1n = bet1[tid];
  float g10 = gam1[0],  b10 = bet1[0];
  float g1e = gam1[512], b1e = bet1[512];
  float bias0 = bias[0];
  float uc = ucol[tid];

  if (tid < TT) mskA[tid] = mask[bA * TT + tid];
  else if (tid < 2 * TT) mskB[tid - TT] = mask[bB * TT + (tid - TT)];
  if (lane == 0){
#pragma unroll
    for (int i = 0; i < 6; i++) redS[wid][i] = 0.f;
  }
  if (tid == 0){ sh_v0A = 0.f; sh_v0B = 0.f; }
  __syncthreads();

  for (int t = 0; t < TT; t++){
    size_t rowA = (size_t)(t * BB + bA);
    size_t rowB = (size_t)(t * BB + bB);

    // ---- P0: issue this step's loads (both rows)
    float lwA = bf2f(lnXW[rowA * NPAD + tid]);
    float lwB = bf2f(lnXW[rowB * NPAD + tid]);
    float lw0A = bf2f(lnXW[rowA * NPAD]);
    float lw0B = bf2f(lnXW[rowB * NPAD]);
    float lw5A = bf2f(lnXW[rowA * NPAD + 512]);
    float lw5B = bf2f(lnXW[rowB * NPAD + 512]);
    float xuA = bf2f(vbuf[rowA * NPAD + tid]);
    float xuB = bf2f(vbuf[rowB * NPAD + tid]);
    float xu5A = bf2f(vbuf[rowA * NPAD + 512]);
    float xu5B = bf2f(vbuf[rowB * NPAD + 512]);
    float xloA, xhiA, xloB, xhiB;
    if (layer == 0){
      xloA = x[((size_t)(bA * TT + t)) * II + tid]; xhiA = 0.f;
      xloB = x[((size_t)(bB * TT + t)) * II + tid]; xhiB = 0.f;
    } else {
      xloA = h_seq[rowA * DD + tid]; xhiA = h_seq[rowA * DD + 512 + tid];
      xloB = h_seq[rowB * DD + tid]; xhiB = h_seq[rowB * DD + 512 + tid];
    }
    float fkpA = 0.f, fknA = 0.f, hvpA = 1.f;
    float fkpB = 0.f, fknB = 0.f, hvpB = 1.f;
    if (layer > 0){
      fkpA = fkbuf[t * BB + bA];
      fknA = (t + 1 < TT) ? fkbuf[(t + 1) * BB + bA] : 0.f;
      hvpA = hvbuf[t * BB + bA];
      fkpB = fkbuf[t * BB + bB];
      fknB = (t + 1 < TT) ? fkbuf[(t + 1) * BB + bB] : 0.f;
      hvpB = hvbuf[t * BB + bB];
    }
    int mrawA = mskA[t], mprevA = (t > 0) ? mskA[t - 1] : 0;
    int mrawB = mskB[t], mprevB = (t > 0) ? mskB[t - 1] : 0;

    // ---- P1: uniform col-512 updates (prev step), LN stats, gates
    if (t > 0){
      float y5A = 0.f, y5B = 0.f;
#pragma unroll
      for (int w = 0; w < 8; w++){ y5A += redS[w][2]; y5B += redS[w][5]; }
      float nA = hoA * v5A + xoA * xu5pA + boA * y5A;
      float nB = hoB * v5B + xoB * xu5pB + boB * y5B;
      if (mkpA) v5A = nA;
      if (mkpB) v5B = nB;
      if (tid == 0 && !lastL){
        vbuf[(rowA - BB) * NPAD + 512] = f2bf(v5A);
        vbuf[(rowB - BB) * NPAD + 512] = f2bf(v5B);
      }
    }
    float SA = 0.f, QA = 0.f, SB = 0.f, QB = 0.f;
#pragma unroll
    for (int w = 0; w < 8; w++){
      SA += redS[w][0]; QA += redS[w][1];
      SB += redS[w][3]; QB += redS[w][4];
    }
    SA += v5A; QA += v5A * v5A;
    SB += v5B; QB += v5B * v5B;
    float v0A = sh_v0A, v0B = sh_v0B;
    float meanA = SA * (1.f / 513.f);
    float varA  = QA * (1.f / 513.f) - meanA * meanA;
    float invA  = 1.f / (sqrtf(varA + EPSL) + EPSL);
    float meanB = SB * (1.f / 513.f);
    float varB  = QB * (1.f / 513.f) - meanB * meanB;
    float invB  = 1.f / (sqrtf(varB + EPSL) + EPSL);

    bool mkA  = mrawA > 0;
    bool mk2A = (t > 0) && (mprevA > 0) && !mkA;
    bool mkB  = mrawB > 0;
    bool mk2B = (t > 0) && (mprevB > 0) && !mkB;

    float s20A = (v0A - meanA) * invA * g10 + b10;
    float fkbA = hsig(lw0A + s20A);
    float ft1A = hsig(s20A + bias0);
    float fkA = fkpA + (1.f - fkpA) * (fkcA * fkbA + (1.f - fkcA) * ft1A);
    if (mk2A) fkA = 0.f;
    float h_oA = hvcA * fkA * (fknA + (1.f - fknA) * (1.f - hvpA));
    float x_oA = hvpA * (1.f - fknA) * (1.f - fkA + fkA * (1.f - hvcA));
    float boA_ = (1.f - fknA) * fkA * hvcA * hvpA;
    float hvA = 1.f - (1.f - h_oA) * (1.f - x_oA) * (1.f - boA_);
    fkcA = mkA ? fkA : fkcA;
    hvcA = mkA ? hvA : hvcA;
    if (mk2A) fkcA = 0.f;

    float s20B = (v0B - meanB) * invB * g10 + b10;
    float fkbB = hsig(lw0B + s20B);
    float ft1B = hsig(s20B + bias0);
    float fkB = fkpB + (1.f - fkpB) * (fkcB * fkbB + (1.f - fkcB) * ft1B);
    if (mk2B) fkB = 0.f;
    float h_oB = hvcB * fkB * (fknB + (1.f - fknB) * (1.f - hvpB));
    float x_oB = hvpB * (1.f - fknB) * (1.f - fkB + fkB * (1.f - hvcB));
    float boB_ = (1.f - fknB) * fkB * hvcB * hvpB;
    float hvB = 1.f - (1.f - h_oB) * (1.f - x_oB) * (1.f - boB_);
    fkcB = mkB ? fkB : fkcB;
    hvcB = mkB ? hvB : hvcB;
    if (mk2B) fkcB = 0.f;

    // ---- P2: LN apply + tanh; stage f16 + f32 (both rows)
    {
      float thA = ftanh(lwA + (svA - meanA) * invA * g1n + b1n);
      float thB = ftanh(lwB + (svB - meanB) * invB * g1n + b1n);
      if (tid == 0){
        float theA = ftanh(lw5A + (v5A - meanA) * invA * g1e + b1e);
        float theB = ftanh(lw5B + (v5B - meanB) * invB * g1e + b1e);
        tanhA[511] = __builtin_bit_cast(ushort, (_Float16)theA);
        tanhB[511] = __builtin_bit_cast(ushort, (_Float16)theB);
        tvfA[511] = theA; tvfB[511] = theB;
      } else {
        tanhA[tid - 1] = __builtin_bit_cast(ushort, (_Float16)thA);
        tanhB[tid - 1] = __builtin_bit_cast(ushort, (_Float16)thB);
        tvfA[tid - 1] = thA; tvfB[tid - 1] = thB;
      }
    }
    __syncthreads();   // B1: tanh staged

    // ---- P3: dual-row GEMV — one U load feeds both rows
    float yA0 = 0.f, yA1 = 0.f, yA2 = 0.f, yA3 = 0.f;
    float yB0 = 0.f, yB1 = 0.f, yB2 = 0.f, yB3 = 0.f;
    {
      const uint4* up = (const uint4*)Upk4 + tid;
      const uint4* ta = (const uint4*)tanhA;
      const uint4* tb = (const uint4*)tanhB;
#pragma unroll 8
      for (int c = 0; c < 64; c++){
        uint4 uu = up[(size_t)c * 512];   // coalesced 16B/lane, serves 2 rows
        uint4 t1 = ta[c];
        uint4 t2 = tb[c];
        yA0 = dot2(t1.x, uu.x, yA0);  yB0 = dot2(t2.x, uu.x, yB0);
        yA1 = dot2(t1.y, uu.y, yA1);  yB1 = dot2(t2.y, uu.y, yB1);
        yA2 = dot2(t1.z, uu.z, yA2);  yB2 = dot2(t2.z, uu.z, yB2);
        yA3 = dot2(t1.w, uu.w, yA3);  yB3 = dot2(t2.w, uu.w, yB3);
      }
    }
    float yA = (yA0 + yA1) + (yA2 + yA3);
    float yB = (yB0 + yB1) + (yB2 + yB3);

    // ---- P4: state updates + stream writes + end-of-step 6-value reduce
    float thhA = tvfA[tid], thhB = tvfB[tid];
    float nvA = h_oA * svA + x_oA * xuA + boA_ * yA;
    float nvB = h_oB * svB + x_oB * xuB + boB_ * yB;
    if (mkA) svA = nvA;
    if (mkB) svB = nvB;
    float nhloA = h_oA * hloA + x_oA * xloA;
    float nhhiA = h_oA * hhiA + x_oA * xhiA + boA_ * thhA;
    if (mkA){ hloA = nhloA; hhiA = nhhiA; }
    float nhloB = h_oB * hloB + x_oB * xloB;
    float nhhiB = h_oB * hhiB + x_oB * xhiB + boB_ * thhB;
    if (mkB){ hloB = nhloB; hhiB = nhhiB; }
    if (!lastL){
      vbuf[rowA * NPAD + tid] = f2bf(svA);
      vbuf[rowB * NPAD + tid] = f2bf(svB);
      h_seq[rowA * DD + tid] = hloA;
      h_seq[rowA * DD + 512 + tid] = hhiA;
      h_seq[rowB * DD + tid] = hloB;
      h_seq[rowB * DD + 512 + tid] = hhiB;
      if (tid == 0){
        fkbuf[t * BB + bA] = fkcA; hvbuf[t * BB + bA] = hvcA;
        fkbuf[t * BB + bB] = fkcB; hvbuf[t * BB + bB] = hvcB;
      }
    }
    if (lastL && t == TT - 1){
      out[bA * HH + tid] = hhiA;
      out[bB * HH + tid] = hhiB;
    }

    hoA = h_oA; xoA = x_oA; boA = boA_; mkpA = mkA ? 1 : 0; xu5pA = xu5A;
    hoB = h_oB; xoB = x_oB; boB = boB_; mkpB = mkB ? 1 : 0; xu5pB = xu5B;

    {
      float aA = svA, qA = svA * svA, pA = thhA * uc;
      float aB = svB, qB = svB * svB, pB = thhB * uc;
#pragma unroll
      for (int m = 1; m < 64; m <<= 1){
        aA += __shfl_xor(aA, m, 64); qA += __shfl_xor(qA, m, 64);
        pA += __shfl_xor(pA, m, 64);
        aB += __shfl_xor(aB, m, 64); qB += __shfl_xor(qB, m, 64);
        pB += __shfl_xor(pB, m, 64);
      }
      if (lane == 0){
        redS[wid][0] = aA; redS[wid][1] = qA; redS[wid][2] = pA;
        redS[wid][3] = aB; redS[wid][4] = qB; redS[wid][5] = pB;
      }
      if (tid == 0){ sh_v0A = svA; sh_v0B = svB; }
    }
    __syncthreads();   // B2 (= next step's start barrier)
  }

  // epilogue: final col-512 updates (t = TT-1)
  if (tid == 0 && !lastL){
    float y5A = 0.f, y5B = 0.f;
#pragma unroll
    for (int w = 0; w < 8; w++){ y5A += redS[w][2]; y5B += redS[w][5]; }
    float nA = hoA * v5A + xoA * xu5pA + boA * y5A;
    float nB = hoB * v5B + xoB * xu5pB + boB * y5B;
    if (mkpA) v5A = nA;
    if (mkpB) v5B = nB;
    vbuf[(size_t)((TT - 1) * BB + bA) * NPAD + 512] = f2bf(v5A);
    vbuf[(size_t)((TT - 1) * BB + bB) * NPAD + 512] = f2bf(v5B);
  }
}

extern "C" void kernel_launch(void* const* d_in, const int* in_sizes, int n_in,
                              void* d_out, int out_size, void* d_ws, size_t ws_size,
                              hipStream_t stream)
{
  (void)in_sizes; (void)n_in; (void)out_size; (void)ws_size;
  const float* x      = (const float*)d_in[0];
  const int*   mask   = (const int*)d_in[1];
  const float* W      = (const float*)d_in[2];
  const float* U      = (const float*)d_in[3];
  const float* bias   = (const float*)d_in[4];
  const float* gammas = (const float*)d_in[5];
  const float* betas  = (const float*)d_in[6];
  float* out = (float*)d_out;

  char* ws = (char*)d_ws;
  size_t off = 0;
  auto alloc = [&](size_t bytes) -> void* {
    void* p = ws + off;
    off += (bytes + 255) & ~(size_t)255;
    return p;
  };
  float*  h_seq = (float*) alloc((size_t)TT * BB * DD * 4);
  ushort* lnXW  = (ushort*)alloc((size_t)TT * BB * NPAD * 2);
  ushort* vbuf  = (ushort*)alloc((size_t)TT * BB * NPAD * 2);
  float*  fkbuf = (float*) alloc((size_t)TT * BB * 4);
  float*  hvbuf = (float*) alloc((size_t)TT * BB * 4);
  ushort* Wpk   = (ushort*)alloc((size_t)128 * NT * 16 * 8 * 2);
  ushort* Upk   = (ushort*)alloc((size_t)128 * NT * 16 * 8 * 2);
  uint*   Upk4  = (uint*)  alloc((size_t)64 * 512 * 4 * 4);
  float*  ucol  = (float*) alloc(512 * 4);

  int npk = 128 * NT * 16 * 8;
  prepack_B<<<dim3((npk + 255) / 256), dim3(256), 0, stream>>>(W, Wpk);
  prepack_B<<<dim3((npk + 255) / 256), dim3(256), 0, stream>>>(U, Upk);
  prepack_Uhi_pk<<<dim3((64 * 512 * 4 + 255) / 256), dim3(256), 0, stream>>>(U, Upk4, ucol);

  const float* g0 = gammas,      *g1 = gammas + NC;
  const float* be0 = betas,      *be1 = betas + NC;

  // layer 0: lnXW = LN(x @ W_lo)+b ; vbuf = x @ U_lo (raw)
  gemm_ln<<<dim3(256), dim3(1024), 0, stream>>>(x, 0, 16, Wpk, lnXW, 1, g0, be0, bias);
  gemm_ln<<<dim3(256), dim3(1024), 0, stream>>>(x, 0, 16, Upk, vbuf, 0, g0, be0, bias);
  rnn_layer<<<dim3(BB / 2), dim3(512), 0, stream>>>(0, x, h_seq, lnXW, vbuf, fkbuf, hvbuf,
                                                    Upk4, ucol, mask, g1, be1, bias, out);
  for (int d = 1; d < 4; d++){
    gemm_ln<<<dim3(256), dim3(1024), 0, stream>>>(h_seq, 1, 32, Wpk, lnXW, 1, g0, be0, bias);
    rnn_layer<<<dim3(BB / 2), dim3(512), 0, stream>>>(d, x, h_seq, lnXW, vbuf, fkbuf, hvbuf,
                                                      Upk4, ucol, mask, g1, be1, bias, out);
  }
}